// Round 1
// baseline (1369.897 us; speedup 1.0000x reference)
//
#include <hip/hip_runtime.h>
#include <math.h>

#define BM 64
#define BN 64
#define BK 32
#define TM 4
#define TN 4
#define MARGIN 0.3f

// ---------------------------------------------------------------------------
// Kernel 1: per-row L2 norm stats.
//   invn[i]  = 1/(||x_i|| + 1e-12)
//   rowsq[i] = ||x_i * invn[i]||^2   (matches reference's sq[] computed on
//                                     normalized rows; ~1.0 up to fp error)
// ---------------------------------------------------------------------------
__global__ void rownorm_k(const float* __restrict__ X, float* __restrict__ invn,
                          float* __restrict__ rowsq, int d) {
    int row = blockIdx.x;
    const float* xr = X + (size_t)row * d;
    float ss = 0.f;
    for (int k = threadIdx.x * 4; k < d; k += blockDim.x * 4) {
        float4 v = *reinterpret_cast<const float4*>(xr + k);
        ss += v.x * v.x + v.y * v.y + v.z * v.z + v.w * v.w;
    }
    for (int m = 32; m > 0; m >>= 1) ss += __shfl_down(ss, m);  // wave64 reduce
    __shared__ float s_part[4];
    int lane = threadIdx.x & 63, wv = threadIdx.x >> 6;
    if (lane == 0) s_part[wv] = ss;
    __syncthreads();
    if (threadIdx.x == 0) {
        float tot = s_part[0] + s_part[1] + s_part[2] + s_part[3];
        float nrm = sqrtf(tot);
        float inv = 1.f / (nrm + 1e-12f);
        invn[row] = inv;
        float s = nrm * inv;
        rowsq[row] = s * s;
    }
}

// ---------------------------------------------------------------------------
// Kernel 2: fused tiled Gram + masked-softmax partial stats.
// Each block computes a 64x64 tile of G = Xn Xn^T (normalization folded into
// LDS staging), then the epilogue converts to distances and accumulates the 4
// per-row softmax accumulators via lane-shuffle reduce + atomicAdd.
// No max-subtraction needed: dist in [0,2] -> exp args bounded.
// ---------------------------------------------------------------------------
__launch_bounds__(256)
__global__ void gram_stats_k(const float* __restrict__ X, const int* __restrict__ tgt,
                             const float* __restrict__ invn, const float* __restrict__ rowsq,
                             float* __restrict__ stats, int n, int d) {
    __shared__ float As[BK][BM + 1];   // +1 pad: staging writes ~2-way banks (free)
    __shared__ float Bs[BK][BN + 1];
    __shared__ int   s_ti[BM], s_tj[BN];
    __shared__ float s_qi[BM], s_qj[BN];

    const int tid = threadIdx.x;
    const int tx = tid & 15, ty = tid >> 4;
    const int nbx = n / BN;
    const int bx = blockIdx.x % nbx;
    const int by = blockIdx.x / nbx;
    const int row0 = by * BM, col0 = bx * BN;

    if (tid < BM) {
        s_ti[tid] = tgt[row0 + tid];
        s_qi[tid] = rowsq[row0 + tid];
    } else if (tid < BM + BN) {
        int t2 = tid - BM;
        s_tj[t2] = tgt[col0 + t2];
        s_qj[t2] = rowsq[col0 + t2];
    }

    float acc[TM][TN];
#pragma unroll
    for (int r = 0; r < TM; ++r)
#pragma unroll
        for (int c = 0; c < TN; ++c) acc[r][c] = 0.f;

    const int kq = tid & 7;    // which float4 chunk of the 32-wide K slice
    const int mr = tid >> 3;   // 0..31 tile row

    for (int k0 = 0; k0 < d; k0 += BK) {
        __syncthreads();  // protect LDS from previous iteration's readers
#pragma unroll
        for (int h = 0; h < 2; ++h) {
            int m = mr + h * 32;
            {
                int g = row0 + m;
                float4 v = *reinterpret_cast<const float4*>(&X[(size_t)g * d + k0 + kq * 4]);
                float iv = invn[g];
                As[kq * 4 + 0][m] = v.x * iv;
                As[kq * 4 + 1][m] = v.y * iv;
                As[kq * 4 + 2][m] = v.z * iv;
                As[kq * 4 + 3][m] = v.w * iv;
            }
            {
                int g = col0 + m;
                float4 v = *reinterpret_cast<const float4*>(&X[(size_t)g * d + k0 + kq * 4]);
                float iv = invn[g];
                Bs[kq * 4 + 0][m] = v.x * iv;
                Bs[kq * 4 + 1][m] = v.y * iv;
                Bs[kq * 4 + 2][m] = v.z * iv;
                Bs[kq * 4 + 3][m] = v.w * iv;
            }
        }
        __syncthreads();
#pragma unroll
        for (int kk = 0; kk < BK; ++kk) {
            float a[TM], b[TN];
#pragma unroll
            for (int r = 0; r < TM; ++r) a[r] = As[kk][ty * TM + r];
#pragma unroll
            for (int c = 0; c < TN; ++c) b[c] = Bs[kk][tx * TN + c];
#pragma unroll
            for (int r = 0; r < TM; ++r)
#pragma unroll
                for (int c = 0; c < TN; ++c) acc[r][c] = fmaf(a[r], b[c], acc[r][c]);
        }
    }

    // Epilogue: distances + masked exp accumulation, reduce across the 16
    // column-lanes (tx) of each wave, one atomicAdd per (row, stat).
#pragma unroll
    for (int r = 0; r < TM; ++r) {
        int i = row0 + ty * TM + r;
        int ti = s_ti[ty * TM + r];
        float sqi = s_qi[ty * TM + r];
        float pd = 0.f, pn = 0.f, nd = 0.f, nn = 0.f;
#pragma unroll
        for (int c = 0; c < TN; ++c) {
            int j = col0 + tx * TN + c;
            int tj = s_tj[tx * TN + c];
            float sqj = s_qj[tx * TN + c];
            float d2 = sqi + sqj - 2.f * acc[r][c];
            float dist = sqrtf(fmaxf(d2, 1e-12f));
            if (ti == tj) {
                if (i != j) {
                    float e = expf(dist);
                    pd += e;
                    pn += e * dist;
                }
            } else {
                float e = expf(-dist);
                nd += e;
                nn += e * dist;
            }
        }
        for (int m = 1; m < 16; m <<= 1) {
            pd += __shfl_xor(pd, m);
            pn += __shfl_xor(pn, m);
            nd += __shfl_xor(nd, m);
            nn += __shfl_xor(nn, m);
        }
        if (tx == 0) {
            atomicAdd(&stats[i * 4 + 0], pd);
            atomicAdd(&stats[i * 4 + 1], pn);
            atomicAdd(&stats[i * 4 + 2], nd);
            atomicAdd(&stats[i * 4 + 3], nn);
        }
    }
}

// ---------------------------------------------------------------------------
// Kernel 3: finalize — loss = mean(relu(pos + MARGIN - neg))
// ---------------------------------------------------------------------------
__global__ void finalize_k(const float* __restrict__ stats, float* __restrict__ out, int n) {
    float s = 0.f;
    for (int i = threadIdx.x; i < n; i += blockDim.x) {
        float pd = stats[i * 4 + 0], pn = stats[i * 4 + 1];
        float nd = stats[i * 4 + 2], nn = stats[i * 4 + 3];
        float v = pn / pd + MARGIN - nn / nd;
        s += fmaxf(v, 0.f);
    }
    for (int m = 32; m > 0; m >>= 1) s += __shfl_down(s, m);
    __shared__ float sp[4];
    int lane = threadIdx.x & 63, wv = threadIdx.x >> 6;
    if (lane == 0) sp[wv] = s;
    __syncthreads();
    if (threadIdx.x == 0) out[0] = (sp[0] + sp[1] + sp[2] + sp[3]) / (float)n;
}

extern "C" void kernel_launch(void* const* d_in, const int* in_sizes, int n_in,
                              void* d_out, int out_size, void* d_ws, size_t ws_size,
                              hipStream_t stream) {
    const float* X = (const float*)d_in[0];
    const int* tgt = (const int*)d_in[1];
    const int n = in_sizes[1];             // 4096
    const int d = in_sizes[0] / n;         // 2048

    float* invn  = (float*)d_ws;           // n floats
    float* rowsq = invn + n;               // n floats
    float* stats = rowsq + n;              // 4n floats (pd, pn, nd, nn per row)

    hipMemsetAsync(stats, 0, (size_t)n * 4 * sizeof(float), stream);
    rownorm_k<<<n, 256, 0, stream>>>(X, invn, rowsq, d);
    const int nblocks = (n / BM) * (n / BN);
    gram_stats_k<<<nblocks, 256, 0, stream>>>(X, tgt, invn, rowsq, stats, n, d);
    finalize_k<<<1, 256, 0, stream>>>(stats, (float*)d_out, n);
}

// Round 2
// 312.867 us; speedup vs baseline: 4.3785x; 4.3785x over previous
//
#include <hip/hip_runtime.h>
#include <math.h>

#define N_MARGIN 0.3f
// Gram GEMM geometry: 128x128 C-tile, BK=64 bf16, 256 threads = 4 waves (2x2),
// each wave 64x64 = 4x4 fragments of mfma_f32_16x16x32_bf16.
#define BM 128
#define BK 64

typedef __attribute__((ext_vector_type(8))) short bf16x8;
typedef __attribute__((ext_vector_type(4))) float f32x4;
typedef __attribute__((address_space(3))) unsigned int lds_uint;
typedef __attribute__((address_space(1))) unsigned int gbl_uint;

// float -> bf16 RNE (no NaN special-casing needed for this data)
static __device__ inline unsigned short f2bf(float f) {
    unsigned int u = __builtin_bit_cast(unsigned int, f);
    u = (u + 0x7fffu + ((u >> 16) & 1u)) >> 16;
    return (unsigned short)u;
}

// ---------------------------------------------------------------------------
// Kernel 1: per-row L2-normalize + convert to bf16.
//   Xb[i][k] = bf16( X[i][k] / (||X_i|| + 1e-12) )
//   rowsq[i] = ||Xn_i||^2 in fp32 (== reference's sq[i], ~1.0)
// ---------------------------------------------------------------------------
__global__ __launch_bounds__(256)
void norm_cvt_k(const float* __restrict__ X, unsigned short* __restrict__ Xb,
                float* __restrict__ rowsq, int d) {
    const int row = blockIdx.x;
    const int tid = threadIdx.x;
    const float* xr = X + (size_t)row * d;

    float ss = 0.f;
    for (int k = tid * 4; k < d; k += 1024) {
        float4 v = *reinterpret_cast<const float4*>(xr + k);
        ss += v.x * v.x + v.y * v.y + v.z * v.z + v.w * v.w;
    }
    for (int m = 32; m > 0; m >>= 1) ss += __shfl_down(ss, m);
    __shared__ float sp[4];
    __shared__ float s_inv;
    int lane = tid & 63, wv = tid >> 6;
    if (lane == 0) sp[wv] = ss;
    __syncthreads();
    if (tid == 0) {
        float tot = sp[0] + sp[1] + sp[2] + sp[3];
        float nrm = sqrtf(tot);
        float inv = 1.f / (nrm + 1e-12f);
        s_inv = inv;
        float s = nrm * inv;
        rowsq[row] = s * s;
    }
    __syncthreads();
    const float inv = s_inv;

    unsigned short* xb = Xb + (size_t)row * d;
    for (int k = tid * 8; k < d; k += 2048) {
        float4 a = *reinterpret_cast<const float4*>(xr + k);
        float4 b = *reinterpret_cast<const float4*>(xr + k + 4);
        uint4 o;
        o.x = (unsigned)f2bf(a.x * inv) | ((unsigned)f2bf(a.y * inv) << 16);
        o.y = (unsigned)f2bf(a.z * inv) | ((unsigned)f2bf(a.w * inv) << 16);
        o.z = (unsigned)f2bf(b.x * inv) | ((unsigned)f2bf(b.y * inv) << 16);
        o.w = (unsigned)f2bf(b.z * inv) | ((unsigned)f2bf(b.w * inv) << 16);
        *reinterpret_cast<uint4*>(xb + k) = o;
    }
}

// ---------------------------------------------------------------------------
// Kernel 2: bf16 MFMA Gram tile + fused masked-softmax partial stats.
// LDS rows are 128 B (BK=64 bf16); XOR swizzle byte ^= ((row&7)<<4) applied
// as: linear global_load_lds dest + inverse-swizzled GLOBAL source addresses
// + swizzled ds_read (both-sides rule).
// ---------------------------------------------------------------------------
__global__ __launch_bounds__(256)
void gram_stats_k(const unsigned short* __restrict__ Xb, const int* __restrict__ tgt,
                  const float* __restrict__ rowsq, float* __restrict__ stats,
                  int n, int d) {
    __shared__ alignas(16) unsigned short As[BM * BK];   // [row][slot] 128B rows
    __shared__ alignas(16) unsigned short Bs[BM * BK];
    __shared__ int   s_ti[BM], s_tj[BM];
    __shared__ float s_qi[BM], s_qj[BM];

    const int tid = threadIdx.x;
    const int lane = tid & 63;
    const int w = tid >> 6;          // wave 0..3
    const int wr = w >> 1, wc = w & 1;

    const int nbx = n / BM;
    const int bx = blockIdx.x % nbx;
    const int by = blockIdx.x / nbx;
    const int row0 = by * BM, col0 = bx * BM;

    if (tid < BM) {
        s_ti[tid] = tgt[row0 + tid];
        s_qi[tid] = rowsq[row0 + tid];
    } else {
        int t2 = tid - BM;
        s_tj[t2] = tgt[col0 + t2];
        s_qj[t2] = rowsq[col0 + t2];
    }

    f32x4 acc[4][4];
#pragma unroll
    for (int a = 0; a < 4; ++a)
#pragma unroll
        for (int b = 0; b < 4; ++b) acc[a][b] = (f32x4){0.f, 0.f, 0.f, 0.f};

    // staging lane map: instruction i covers LDS rows 8i..8i+7 (1024 B);
    // lane l -> row 8i + (l>>3), physical slot l&7, global chunk (l&7)^(l>>3)
    const int st_r = lane >> 3;                     // 0..7 row within group
    const int st_s = (lane & 7) ^ st_r;             // global 16B-chunk index
    // ds_read slot xor term (row&7 == lane&7 since row = ..16*fr + (lane&15))
    const int rd_x = lane & 7;
    const int rd_k = lane >> 4;                     // k-chunk within K=32

    for (int k0 = 0; k0 < d; k0 += BK) {
#pragma unroll
        for (int q = 0; q < 4; ++q) {
            int i = 4 * w + q;
            const unsigned short* ga =
                Xb + (size_t)(row0 + 8 * i + st_r) * d + k0 + st_s * 8;
            __builtin_amdgcn_global_load_lds((const gbl_uint*)ga,
                                             (lds_uint*)(As + i * 512), 16, 0, 0);
            const unsigned short* gb =
                Xb + (size_t)(col0 + 8 * i + st_r) * d + k0 + st_s * 8;
            __builtin_amdgcn_global_load_lds((const gbl_uint*)gb,
                                             (lds_uint*)(Bs + i * 512), 16, 0, 0);
        }
        __syncthreads();

#pragma unroll
        for (int ks = 0; ks < 2; ++ks) {
            const int slot = (ks * 4 + rd_k) ^ rd_x;
            bf16x8 af[4], bf[4];
#pragma unroll
            for (int fr = 0; fr < 4; ++fr) {
                int rA = wr * 64 + fr * 16 + (lane & 15);
                af[fr] = *reinterpret_cast<const bf16x8*>(&As[rA * 64 + slot * 8]);
                int rB = wc * 64 + fr * 16 + (lane & 15);
                bf[fr] = *reinterpret_cast<const bf16x8*>(&Bs[rB * 64 + slot * 8]);
            }
#pragma unroll
            for (int fr = 0; fr < 4; ++fr)
#pragma unroll
                for (int nc = 0; nc < 4; ++nc)
                    acc[fr][nc] = __builtin_amdgcn_mfma_f32_16x16x32_bf16(
                        af[fr], bf[nc], acc[fr][nc], 0, 0, 0);
        }
        __syncthreads();
    }

    // Epilogue: C[row][col]: col = lane&15 (+nc*16), row = (lane>>4)*4 + j (+fr*16)
    int tjv[4]; float qjv[4];
#pragma unroll
    for (int nc = 0; nc < 4; ++nc) {
        int cloc = wc * 64 + nc * 16 + (lane & 15);
        tjv[nc] = s_tj[cloc];
        qjv[nc] = s_qj[cloc];
    }
#pragma unroll
    for (int fr = 0; fr < 4; ++fr) {
#pragma unroll
        for (int j = 0; j < 4; ++j) {
            int rloc = wr * 64 + fr * 16 + (lane >> 4) * 4 + j;
            int grow = row0 + rloc;
            int ti = s_ti[rloc];
            float sqi = s_qi[rloc];
            float pd = 0.f, pn = 0.f, nd = 0.f, nn = 0.f;
#pragma unroll
            for (int nc = 0; nc < 4; ++nc) {
                int gcol = col0 + wc * 64 + nc * 16 + (lane & 15);
                float g = acc[fr][nc][j];
                float d2 = sqi + qjv[nc] - 2.f * g;
                float dist = sqrtf(fmaxf(d2, 1e-12f));
                if (ti == tjv[nc]) {
                    if (grow != gcol) {
                        float e = __expf(dist);
                        pd += e; pn += e * dist;
                    }
                } else {
                    float e = __expf(-dist);
                    nd += e; nn += e * dist;
                }
            }
            for (int m = 1; m < 16; m <<= 1) {
                pd += __shfl_xor(pd, m);
                pn += __shfl_xor(pn, m);
                nd += __shfl_xor(nd, m);
                nn += __shfl_xor(nn, m);
            }
            if ((lane & 15) == 0) {
                atomicAdd(&stats[grow * 4 + 0], pd);
                atomicAdd(&stats[grow * 4 + 1], pn);
                atomicAdd(&stats[grow * 4 + 2], nd);
                atomicAdd(&stats[grow * 4 + 3], nn);
            }
        }
    }
}

// ---------------------------------------------------------------------------
// Kernel 3: finalize — loss = mean(relu(pos + MARGIN - neg))
// ---------------------------------------------------------------------------
__global__ void finalize_k(const float* __restrict__ stats, float* __restrict__ out, int n) {
    float s = 0.f;
    for (int i = threadIdx.x; i < n; i += blockDim.x) {
        float pd = stats[i * 4 + 0], pn = stats[i * 4 + 1];
        float nd = stats[i * 4 + 2], nn = stats[i * 4 + 3];
        float v = pn / pd + N_MARGIN - nn / nd;
        s += fmaxf(v, 0.f);
    }
    for (int m = 32; m > 0; m >>= 1) s += __shfl_down(s, m);
    __shared__ float sp[4];
    int lane = threadIdx.x & 63, wv = threadIdx.x >> 6;
    if (lane == 0) sp[wv] = s;
    __syncthreads();
    if (threadIdx.x == 0) out[0] = (sp[0] + sp[1] + sp[2] + sp[3]) / (float)n;
}

extern "C" void kernel_launch(void* const* d_in, const int* in_sizes, int n_in,
                              void* d_out, int out_size, void* d_ws, size_t ws_size,
                              hipStream_t stream) {
    const float* X = (const float*)d_in[0];
    const int* tgt = (const int*)d_in[1];
    const int n = in_sizes[1];             // 4096
    const int d = in_sizes[0] / n;         // 2048

    unsigned short* Xb = (unsigned short*)d_ws;          // n*d bf16 (16 MB)
    float* rowsq = (float*)(Xb + (size_t)n * d);         // n floats
    float* stats = rowsq + n;                            // 4n floats

    hipMemsetAsync(stats, 0, (size_t)n * 4 * sizeof(float), stream);
    norm_cvt_k<<<n, 256, 0, stream>>>(X, Xb, rowsq, d);
    const int nblocks = (n / BM) * (n / BM);
    gram_stats_k<<<nblocks, 256, 0, stream>>>(Xb, tgt, rowsq, stats, n, d);
    finalize_k<<<1, 256, 0, stream>>>(stats, (float*)d_out, n);
}

// Round 3
// 243.349 us; speedup vs baseline: 5.6293x; 1.2857x over previous
//
#include <hip/hip_runtime.h>
#include <math.h>

#define N_MARGIN 0.3f
// Gram GEMM geometry: 128x128 C-tile, BK=64 bf16, 256 threads = 4 waves (2x2),
// each wave 64x64 = 4x4 fragments of mfma_f32_16x16x32_bf16.
// Symmetry: only upper-triangular block tiles (by <= bx) are computed; the
// epilogue scatters off-diagonal tiles into both row-block and col-block stats.
#define BM 128
#define BK 64

typedef __attribute__((ext_vector_type(8))) short bf16x8;
typedef __attribute__((ext_vector_type(4))) float f32x4;
typedef __attribute__((address_space(3))) unsigned int lds_uint;
typedef __attribute__((address_space(1))) unsigned int gbl_uint;

// float -> bf16 RNE
static __device__ inline unsigned short f2bf(float f) {
    unsigned int u = __builtin_bit_cast(unsigned int, f);
    u = (u + 0x7fffu + ((u >> 16) & 1u)) >> 16;
    return (unsigned short)u;
}

// ---------------------------------------------------------------------------
// Kernel 1: per-row L2-normalize + convert to bf16.
// ---------------------------------------------------------------------------
__global__ __launch_bounds__(256)
void norm_cvt_k(const float* __restrict__ X, unsigned short* __restrict__ Xb,
                float* __restrict__ rowsq, int d) {
    const int row = blockIdx.x;
    const int tid = threadIdx.x;
    const float* xr = X + (size_t)row * d;

    float ss = 0.f;
    for (int k = tid * 4; k < d; k += 1024) {
        float4 v = *reinterpret_cast<const float4*>(xr + k);
        ss += v.x * v.x + v.y * v.y + v.z * v.z + v.w * v.w;
    }
    for (int m = 32; m > 0; m >>= 1) ss += __shfl_down(ss, m);
    __shared__ float sp[4];
    __shared__ float s_inv;
    int lane = tid & 63, wv = tid >> 6;
    if (lane == 0) sp[wv] = ss;
    __syncthreads();
    if (tid == 0) {
        float tot = sp[0] + sp[1] + sp[2] + sp[3];
        float nrm = sqrtf(tot);
        float inv = 1.f / (nrm + 1e-12f);
        s_inv = inv;
        float s = nrm * inv;
        rowsq[row] = s * s;
    }
    __syncthreads();
    const float inv = s_inv;

    unsigned short* xb = Xb + (size_t)row * d;
    for (int k = tid * 8; k < d; k += 2048) {
        float4 a = *reinterpret_cast<const float4*>(xr + k);
        float4 b = *reinterpret_cast<const float4*>(xr + k + 4);
        uint4 o;
        o.x = (unsigned)f2bf(a.x * inv) | ((unsigned)f2bf(a.y * inv) << 16);
        o.y = (unsigned)f2bf(a.z * inv) | ((unsigned)f2bf(a.w * inv) << 16);
        o.z = (unsigned)f2bf(b.x * inv) | ((unsigned)f2bf(b.y * inv) << 16);
        o.w = (unsigned)f2bf(b.z * inv) | ((unsigned)f2bf(b.w * inv) << 16);
        *reinterpret_cast<uint4*>(xb + k) = o;
    }
}

// ---------------------------------------------------------------------------
// Kernel 2: bf16 MFMA Gram tile (upper-triangular only) + fused masked-softmax
// partial stats for rows AND (off-diagonal) mirrored columns.
// LDS swizzle per rule #21: linear global_load_lds dest + inverse-swizzled
// global source + swizzled ds_read.
// ---------------------------------------------------------------------------
__global__ __launch_bounds__(256)
void gram_stats_k(const unsigned short* __restrict__ Xb, const int* __restrict__ tgt,
                  const float* __restrict__ rowsq, float* __restrict__ stats,
                  int n, int d) {
    __shared__ alignas(16) unsigned short As[BM * BK];   // [row][slot] 128B rows
    __shared__ alignas(16) unsigned short Bs[BM * BK];
    __shared__ int   s_ti[BM], s_tj[BM];
    __shared__ float s_qi[BM], s_qj[BM];

    const int tid = threadIdx.x;
    const int lane = tid & 63;
    const int w = tid >> 6;          // wave 0..3
    const int wr = w >> 1, wc = w & 1;

    const int nbx = n / BM;          // 32
    // decode upper-triangular tile index -> (by, bx), bx fast-varying
    int by = 0, rem = blockIdx.x;
    while (rem >= nbx - by) { rem -= nbx - by; ++by; }
    const int bx = by + rem;
    const bool offdiag = (by != bx);
    const int row0 = by * BM, col0 = bx * BM;

    if (tid < BM) {
        s_ti[tid] = tgt[row0 + tid];
        s_qi[tid] = rowsq[row0 + tid];
    } else {
        int t2 = tid - BM;
        s_tj[t2] = tgt[col0 + t2];
        s_qj[t2] = rowsq[col0 + t2];
    }

    f32x4 acc[4][4];
#pragma unroll
    for (int a = 0; a < 4; ++a)
#pragma unroll
        for (int b = 0; b < 4; ++b) acc[a][b] = (f32x4){0.f, 0.f, 0.f, 0.f};

    // staging lane map: instruction i covers LDS rows 8i..8i+7 (1024 B);
    // lane l -> row 8i + (l>>3), physical slot l&7, global chunk (l&7)^(l>>3)
    const int st_r = lane >> 3;
    const int st_s = (lane & 7) ^ st_r;
    const int rd_x = lane & 7;
    const int rd_k = lane >> 4;

    for (int k0 = 0; k0 < d; k0 += BK) {
#pragma unroll
        for (int q = 0; q < 4; ++q) {
            int i = 4 * w + q;
            const unsigned short* ga =
                Xb + (size_t)(row0 + 8 * i + st_r) * d + k0 + st_s * 8;
            __builtin_amdgcn_global_load_lds((const gbl_uint*)ga,
                                             (lds_uint*)(As + i * 512), 16, 0, 0);
            const unsigned short* gb =
                Xb + (size_t)(col0 + 8 * i + st_r) * d + k0 + st_s * 8;
            __builtin_amdgcn_global_load_lds((const gbl_uint*)gb,
                                             (lds_uint*)(Bs + i * 512), 16, 0, 0);
        }
        __syncthreads();

#pragma unroll
        for (int ks = 0; ks < 2; ++ks) {
            const int slot = (ks * 4 + rd_k) ^ rd_x;
            bf16x8 af[4], bf[4];
#pragma unroll
            for (int fr = 0; fr < 4; ++fr) {
                int rA = wr * 64 + fr * 16 + (lane & 15);
                af[fr] = *reinterpret_cast<const bf16x8*>(&As[rA * 64 + slot * 8]);
                int rB = wc * 64 + fr * 16 + (lane & 15);
                bf[fr] = *reinterpret_cast<const bf16x8*>(&Bs[rB * 64 + slot * 8]);
            }
#pragma unroll
            for (int fr = 0; fr < 4; ++fr)
#pragma unroll
                for (int nc = 0; nc < 4; ++nc)
                    acc[fr][nc] = __builtin_amdgcn_mfma_f32_16x16x32_bf16(
                        af[fr], bf[nc], acc[fr][nc], 0, 0, 0);
        }
        __syncthreads();
    }

    // ------------------------------------------------------------------
    // Epilogue. C[row][col]: col = lane&15 (+nc*16 +wc*64),
    //                        row = (lane>>4)*4 + j (+fr*16 +wr*64).
    // Row stats: reduce over columns = in-thread nc + shfl_xor {1,2,4,8}.
    // Col stats (off-diag mirror): reduce over rows = in-thread (fr,j) +
    //                              shfl_xor {16,32}.
    // ------------------------------------------------------------------
    int tjv[4]; float qjv[4];
#pragma unroll
    for (int nc = 0; nc < 4; ++nc) {
        int cloc = wc * 64 + nc * 16 + (lane & 15);
        tjv[nc] = s_tj[cloc];
        qjv[nc] = s_qj[cloc];
    }
    float cs0[4], cs1[4], cs2[4], cs3[4];   // per-nc col partials: pd,pn,nd,nn
#pragma unroll
    for (int nc = 0; nc < 4; ++nc) { cs0[nc] = 0.f; cs1[nc] = 0.f; cs2[nc] = 0.f; cs3[nc] = 0.f; }

#pragma unroll
    for (int fr = 0; fr < 4; ++fr) {
#pragma unroll
        for (int j = 0; j < 4; ++j) {
            int rloc = wr * 64 + fr * 16 + (lane >> 4) * 4 + j;
            int grow = row0 + rloc;
            int ti = s_ti[rloc];
            float sqi = s_qi[rloc];
            float pd = 0.f, pn = 0.f, nd = 0.f, nn = 0.f;
#pragma unroll
            for (int nc = 0; nc < 4; ++nc) {
                int gcol = col0 + wc * 64 + nc * 16 + (lane & 15);
                float g = acc[fr][nc][j];
                float d2 = sqi + qjv[nc] - 2.f * g;
                float dist = sqrtf(fmaxf(d2, 1e-12f));
                if (ti == tjv[nc]) {
                    if (grow != gcol) {
                        float e = __expf(dist);
                        pd += e; pn += e * dist;
                        cs0[nc] += e; cs1[nc] += e * dist;
                    }
                } else {
                    float e = __expf(-dist);
                    nd += e; nn += e * dist;
                    cs2[nc] += e; cs3[nc] += e * dist;
                }
            }
            for (int m = 1; m < 16; m <<= 1) {
                pd += __shfl_xor(pd, m);
                pn += __shfl_xor(pn, m);
                nd += __shfl_xor(nd, m);
                nn += __shfl_xor(nn, m);
            }
            if ((lane & 15) == 0) {
                atomicAdd(&stats[grow * 4 + 0], pd);
                atomicAdd(&stats[grow * 4 + 1], pn);
                atomicAdd(&stats[grow * 4 + 2], nd);
                atomicAdd(&stats[grow * 4 + 3], nn);
            }
        }
    }

    if (offdiag) {
#pragma unroll
        for (int nc = 0; nc < 4; ++nc) {
            float a = cs0[nc], b = cs1[nc], c = cs2[nc], e = cs3[nc];
            for (int m = 16; m < 64; m <<= 1) {
                a += __shfl_xor(a, m);
                b += __shfl_xor(b, m);
                c += __shfl_xor(c, m);
                e += __shfl_xor(e, m);
            }
            if (lane < 16) {
                int gcol = col0 + wc * 64 + nc * 16 + lane;
                atomicAdd(&stats[gcol * 4 + 0], a);
                atomicAdd(&stats[gcol * 4 + 1], b);
                atomicAdd(&stats[gcol * 4 + 2], c);
                atomicAdd(&stats[gcol * 4 + 3], e);
            }
        }
    }
}

// ---------------------------------------------------------------------------
// Kernel 3: finalize — loss = mean(relu(pos + MARGIN - neg))
// ---------------------------------------------------------------------------
__global__ void finalize_k(const float* __restrict__ stats, float* __restrict__ out, int n) {
    float s = 0.f;
    for (int i = threadIdx.x; i < n; i += blockDim.x) {
        float pd = stats[i * 4 + 0], pn = stats[i * 4 + 1];
        float nd = stats[i * 4 + 2], nn = stats[i * 4 + 3];
        float v = pn / pd + N_MARGIN - nn / nd;
        s += fmaxf(v, 0.f);
    }
    for (int m = 32; m > 0; m >>= 1) s += __shfl_down(s, m);
    __shared__ float sp[4];
    int lane = threadIdx.x & 63, wv = threadIdx.x >> 6;
    if (lane == 0) sp[wv] = s;
    __syncthreads();
    if (threadIdx.x == 0) out[0] = (sp[0] + sp[1] + sp[2] + sp[3]) / (float)n;
}

extern "C" void kernel_launch(void* const* d_in, const int* in_sizes, int n_in,
                              void* d_out, int out_size, void* d_ws, size_t ws_size,
                              hipStream_t stream) {
    const float* X = (const float*)d_in[0];
    const int* tgt = (const int*)d_in[1];
    const int n = in_sizes[1];             // 4096
    const int d = in_sizes[0] / n;         // 2048

    unsigned short* Xb = (unsigned short*)d_ws;          // n*d bf16 (16 MB)
    float* rowsq = (float*)(Xb + (size_t)n * d);         // n floats
    float* stats = rowsq + n;                            // 4n floats

    hipMemsetAsync(stats, 0, (size_t)n * 4 * sizeof(float), stream);
    norm_cvt_k<<<n, 256, 0, stream>>>(X, Xb, rowsq, d);
    const int nbx = n / BM;                              // 32
    const int nblocks = nbx * (nbx + 1) / 2;             // 528 upper-tri tiles
    gram_stats_k<<<nblocks, 256, 0, stream>>>(Xb, tgt, rowsq, stats, n, d);
    finalize_k<<<1, 256, 0, stream>>>(stats, (float*)d_out, n);
}